// Round 3
// baseline (255.571 us; speedup 1.0000x reference)
//
#include <hip/hip_runtime.h>
#include <math.h>

#define S_   4096
#define H_   8
#define D_   64
#define HD_  512
#define NCH  256   // chunks per batch
#define LCH  16    // seq steps per chunk
#define RC   128   // rows per chunk = LCH*H_  (h-major: row = h*16 + s)
#define NCOL 2048  // scan columns = B * H * D

typedef __bf16 bf16x8 __attribute__((ext_vector_type(8)));
typedef __bf16 bf16x2 __attribute__((ext_vector_type(2)));
typedef float  f32x4  __attribute__((ext_vector_type(4)));

__device__ __forceinline__ float sigm(float v) { return 1.f / (1.f + __expf(-v)); }

// XOR-swizzled byte offset into the 128x128 bf16 A-tile (row stride 256B).
__device__ __forceinline__ int swzA(int row, int bytecol) {
  return row * 256 + (bytecol ^ ((row & 7) << 4));
}

// ---------------- K0: transpose weights to bf16 [n][k] ----------------
__global__ __launch_bounds__(256) void k_wt(const float* __restrict__ Wh,
                                            const float* __restrict__ Wo,
                                            __bf16* __restrict__ Wth,
                                            __bf16* __restrict__ Wto) {
  int idx = blockIdx.x * 256 + threadIdx.x;   // 0..32767
  if (idx < 24576) {
    int k = idx / 192, n = idx % 192;
    Wth[n * 128 + k] = (__bf16)Wh[idx];
  } else {
    int j = idx - 24576;                       // 0..8191, W_og[k][n], n<64
    int k = j >> 6, n = j & 63;
    Wto[n * 128 + k] = (__bf16)Wo[j];
  }
}

// ---------------- K1: per-chunk sums of x ----------------
__global__ __launch_bounds__(512) void k_chunk_sums(const float* __restrict__ x,
                                                    float* __restrict__ sums) {
  const int b = blockIdx.x >> 8, c = blockIdx.x & 255;
  const int t = threadIdx.x;
  const float* p = x + ((size_t)b * S_ + c * LCH) * HD_ + t;
  float acc = 0.f;
  #pragma unroll
  for (int i = 0; i < LCH; ++i) acc += p[(size_t)i * HD_];
  sums[((size_t)b * NCH + c) * HD_ + t] = acc;
}

// ---------------- 3-level exclusive scan of chunk sums (x offsets) -----------
__global__ __launch_bounds__(256) void kx_l1(const float* __restrict__ sums,
                                             float* __restrict__ gx) {
  int w = blockIdx.x * 256 + threadIdx.x;    // 0..32767
  int grp = w >> 11, col = w & 2047;
  int b = col >> 9, hd = col & 511;
  float s = 0.f;
  #pragma unroll
  for (int i = 0; i < 16; ++i)
    s += sums[((size_t)(b * NCH + grp * 16 + i)) * HD_ + hd];
  gx[grp * NCOL + col] = s;
}
__global__ __launch_bounds__(256) void kx_l2(float* __restrict__ gx) {
  int col = blockIdx.x * 256 + threadIdx.x;  // 0..2047
  float run = 0.f;
  #pragma unroll
  for (int g = 0; g < 16; ++g) {
    float v = gx[g * NCOL + col];
    gx[g * NCOL + col] = run;
    run += v;
  }
}
__global__ __launch_bounds__(256) void kx_l3(float* __restrict__ sums,
                                             const float* __restrict__ gx) {
  int w = blockIdx.x * 256 + threadIdx.x;
  int grp = w >> 11, col = w & 2047;
  int b = col >> 9, hd = col & 511;
  float run = gx[grp * NCOL + col];
  #pragma unroll
  for (int i = 0; i < 16; ++i) {
    size_t idx = ((size_t)(b * NCH + grp * 16 + i)) * HD_ + hd;
    float v = sums[idx];
    sums[idx] = run;
    run += v;
  }
}

// ---------------- shared device body: LN -> LDS A-tile, gates GEMM, scan -----
// WRITE_TOT=true : write only per-chunk totals cA/cB.
// WRITE_TOT=false: fill per-row scan prefixes abA/abB (registers).
template <bool WRITE_TOT>
__device__ __forceinline__ void ln_gates(const float* __restrict__ x,
                                         const float* __restrict__ offs,
                                         const float* __restrict__ gamma,
                                         const float* __restrict__ beta,
                                         const __bf16* __restrict__ Wth,
                                         const float* __restrict__ bh,
                                         char* Al, float2* red,
                                         int b, int c, int cid,
                                         float (&abA)[2][16], float (&abB)[2][16],
                                         float* __restrict__ cA,
                                         float* __restrict__ cB) {
  const int t = threadIdx.x;
  const int wave = t >> 6, lane = t & 63;
  const int quad = lane >> 4, l16 = lane & 15;

  // ---- P0: running prefix + LayerNorm -> A=[x|ln] tile in LDS ----
  {
    const int hd0 = 2 * t;                 // adjacent columns, same head/row
    const int h = hd0 >> 6, d0 = hd0 & 63; // d0 even
    float2 rr = *(const float2*)(offs + (size_t)(b * NCH + c) * HD_ + hd0);
    float run0 = rr.x, run1 = rr.y;
    float2 gg = *(const float2*)(gamma + hd0);
    float2 be = *(const float2*)(beta + hd0);
    const size_t xbase = ((size_t)b * S_ + c * LCH) * HD_;
    float2 xv = *(const float2*)(x + xbase + hd0);
    for (int s = 0; s < LCH; ++s) {
      float2 xn = make_float2(0.f, 0.f);
      if (s < LCH - 1) xn = *(const float2*)(x + xbase + (size_t)(s + 1) * HD_ + hd0);
      float v = run0 + run1;
      float v2 = fmaf(run0, run0, run1 * run1);
      #pragma unroll
      for (int o = 32; o; o >>= 1) { v += __shfl_xor(v, o); v2 += __shfl_xor(v2, o); }
      if (lane == 0) red[(s & 1) * 4 + wave] = make_float2(v, v2);
      __syncthreads();
      const float2* rb = red + (s & 1) * 4;
      float s1 = rb[0].x + rb[1].x + rb[2].x + rb[3].x;
      float s2 = rb[0].y + rb[1].y + rb[2].y + rb[3].y;
      float m = s1 * (1.f / HD_);
      float var = fmaf(-m, m, s2 * (1.f / HD_));
      float inv = rsqrtf(var + 1e-5f);
      int row = h * 16 + s;
      bf16x2 px = { (__bf16)xv.x, (__bf16)xv.y };
      bf16x2 pl = { (__bf16)((run0 - m) * inv * gg.x + be.x),
                    (__bf16)((run1 - m) * inv * gg.y + be.y) };
      *(bf16x2*)(Al + swzA(row, d0 * 2)) = px;
      *(bf16x2*)(Al + swzA(row, 128 + d0 * 2)) = pl;
      run0 += xv.x; run1 += xv.y;
      xv = xn;
    }
  }
  __syncthreads();

  // ---- P1: gates GEMM (3 register-lean N-passes) + chunk-local scan ----
  #pragma unroll
  for (int mi = 0; mi < 2; ++mi) {
    const int mt = wave * 2 + mi;          // head
    const int arow = mt * 16 + l16;
    float fv[16], iv[16];
    // pass F (N cols 64..127)
    {
      f32x4 acc[4];
      #pragma unroll
      for (int nt = 0; nt < 4; ++nt) acc[nt] = (f32x4){0.f, 0.f, 0.f, 0.f};
      #pragma unroll
      for (int ks = 0; ks < 4; ++ks) {
        bf16x8 af = *(const bf16x8*)(Al + swzA(arow, ks * 64 + quad * 16));
        #pragma unroll
        for (int nt = 0; nt < 4; ++nt) {
          bf16x8 bf_ = *(const bf16x8*)(Wth + ((4 + nt) * 16 + l16) * 128 + ks * 32 + quad * 8);
          acc[nt] = __builtin_amdgcn_mfma_f32_16x16x32_bf16(af, bf_, acc[nt], 0, 0, 0);
        }
      }
      #pragma unroll
      for (int nt = 0; nt < 4; ++nt) {
        float bb_ = bh[64 + nt * 16 + l16];
        #pragma unroll
        for (int r = 0; r < 4; ++r) fv[nt * 4 + r] = sigm(acc[nt][r] + bb_);
      }
    }
    // pass I (N cols 0..63)
    {
      f32x4 acc[4];
      #pragma unroll
      for (int nt = 0; nt < 4; ++nt) acc[nt] = (f32x4){0.f, 0.f, 0.f, 0.f};
      #pragma unroll
      for (int ks = 0; ks < 4; ++ks) {
        bf16x8 af = *(const bf16x8*)(Al + swzA(arow, ks * 64 + quad * 16));
        #pragma unroll
        for (int nt = 0; nt < 4; ++nt) {
          bf16x8 bf_ = *(const bf16x8*)(Wth + (nt * 16 + l16) * 128 + ks * 32 + quad * 8);
          acc[nt] = __builtin_amdgcn_mfma_f32_16x16x32_bf16(af, bf_, acc[nt], 0, 0, 0);
        }
      }
      #pragma unroll
      for (int nt = 0; nt < 4; ++nt) {
        float bb_ = bh[nt * 16 + l16];
        #pragma unroll
        for (int r = 0; r < 4; ++r) iv[nt * 4 + r] = sigm(acc[nt][r] + bb_);
      }
    }
    // pass H (N cols 128..191): iv becomes g = sigm(i)*relu(h)
    {
      f32x4 acc[4];
      #pragma unroll
      for (int nt = 0; nt < 4; ++nt) acc[nt] = (f32x4){0.f, 0.f, 0.f, 0.f};
      #pragma unroll
      for (int ks = 0; ks < 4; ++ks) {
        bf16x8 af = *(const bf16x8*)(Al + swzA(arow, ks * 64 + quad * 16));
        #pragma unroll
        for (int nt = 0; nt < 4; ++nt) {
          bf16x8 bf_ = *(const bf16x8*)(Wth + ((8 + nt) * 16 + l16) * 128 + ks * 32 + quad * 8);
          acc[nt] = __builtin_amdgcn_mfma_f32_16x16x32_bf16(af, bf_, acc[nt], 0, 0, 0);
        }
      }
      #pragma unroll
      for (int nt = 0; nt < 4; ++nt) {
        float bb_ = bh[128 + nt * 16 + l16];
        #pragma unroll
        for (int r = 0; r < 4; ++r)
          iv[nt * 4 + r] = iv[nt * 4 + r] * fmaxf(acc[nt][r] + bb_, 0.f);
      }
    }
    // segmented affine scan over s (4 regs x 4 quads)
    #pragma unroll
    for (int nt = 0; nt < 4; ++nt) {
      float a = 1.f, bb2 = 0.f, pa[4], pb[4];
      #pragma unroll
      for (int r = 0; r < 4; ++r) {
        float fvv = fv[nt * 4 + r], gvv = iv[nt * 4 + r];
        a = fvv * a;
        bb2 = fmaf(fvv, bb2, gvv);
        pa[r] = a; pb[r] = bb2;
      }
      if constexpr (WRITE_TOT) {
        float TA = 1.f, TB = 0.f;
        #pragma unroll
        for (int q = 0; q < 4; ++q) {
          float Aq = __shfl(a, q * 16 + l16, 64);
          float Bq = __shfl(bb2, q * 16 + l16, 64);
          TB = fmaf(Aq, TB, Bq);
          TA = Aq * TA;
        }
        if (quad == 0) {
          cA[(size_t)cid * HD_ + mt * 64 + nt * 16 + l16] = TA;
          cB[(size_t)cid * HD_ + mt * 64 + nt * 16 + l16] = TB;
        }
      } else {
        float exA = 1.f, exB = 0.f;
        #pragma unroll
        for (int q = 0; q < 3; ++q) {
          float Aq = __shfl(a, q * 16 + l16, 64);
          float Bq = __shfl(bb2, q * 16 + l16, 64);
          if (q < quad) { exB = fmaf(Aq, exB, Bq); exA = Aq * exA; }
        }
        #pragma unroll
        for (int r = 0; r < 4; ++r) {
          abA[mi][nt * 4 + r] = pa[r] * exA;
          abB[mi][nt * 4 + r] = fmaf(pa[r], exB, pb[r]);
        }
      }
    }
  }
}

// ---------------- K4: LN + gates GEMM + chunk scan -> cA/cB only -------------
__global__ __launch_bounds__(256, 4) void k_gates_f(const float* __restrict__ x,
                                                    const float* __restrict__ offs,
                                                    const float* __restrict__ gamma,
                                                    const float* __restrict__ beta,
                                                    const __bf16* __restrict__ Wth,
                                                    const float* __restrict__ bh,
                                                    float* __restrict__ cA,
                                                    float* __restrict__ cB) {
  __shared__ char Al[RC * 256];
  __shared__ float2 red[8];
  const int cid = blockIdx.x, b = cid >> 8, c = cid & 255;
  float abA[2][16], abB[2][16];
  ln_gates<true>(x, offs, gamma, beta, Wth, bh, Al, red, b, c, cid, abA, abB, cA, cB);
}

// ---------------- 3-level cross-chunk cell scan ------------------------------
__global__ __launch_bounds__(256) void kc_l1(const float* __restrict__ cA,
                                             const float* __restrict__ cB,
                                             float* __restrict__ gA,
                                             float* __restrict__ gB) {
  int w = blockIdx.x * 256 + threadIdx.x;
  int grp = w >> 11, col = w & 2047;
  int b = col >> 9, hd = col & 511;
  float Ag = 1.f, Bg = 0.f;
  #pragma unroll
  for (int i = 0; i < 16; ++i) {
    size_t idx = ((size_t)(b * NCH + grp * 16 + i)) * HD_ + hd;
    float Ac = cA[idx], Bc = cB[idx];
    Bg = fmaf(Ac, Bg, Bc);
    Ag = Ac * Ag;
  }
  gA[grp * NCOL + col] = Ag;
  gB[grp * NCOL + col] = Bg;
}
__global__ __launch_bounds__(256) void kc_l2(float* __restrict__ gA,
                                             const float* __restrict__ gB,
                                             const float* __restrict__ initcx) {
  int col = blockIdx.x * 256 + threadIdx.x;   // 0..2047
  int hd = col & 511;
  float run = initcx[hd];
  #pragma unroll
  for (int g = 0; g < 16; ++g) {
    float Ag = gA[g * NCOL + col], Bg = gB[g * NCOL + col];
    gA[g * NCOL + col] = run;                 // group run-in value
    run = fmaf(Ag, run, Bg);
  }
}
__global__ __launch_bounds__(256) void kc_l3(const float* __restrict__ cA,
                                             const float* __restrict__ cB,
                                             const float* __restrict__ gA,
                                             float* __restrict__ cin) {
  int w = blockIdx.x * 256 + threadIdx.x;
  int grp = w >> 11, col = w & 2047;
  int b = col >> 9, hd = col & 511;
  float run = gA[grp * NCOL + col];
  #pragma unroll
  for (int i = 0; i < 16; ++i) {
    size_t idx = ((size_t)(b * NCH + grp * 16 + i)) * HD_ + hd;
    cin[idx] = run;
    run = fmaf(cA[idx], run, cB[idx]);
  }
}

// ---------------- K6: recompute LN+gates, cell emit, og GEMM, out ------------
__global__ __launch_bounds__(256, 4) void k_og_f(const float* __restrict__ x,
                                                 const float* __restrict__ offs,
                                                 const float* __restrict__ gamma,
                                                 const float* __restrict__ beta,
                                                 const __bf16* __restrict__ Wth,
                                                 const __bf16* __restrict__ Wto,
                                                 const float* __restrict__ bh,
                                                 const float* __restrict__ bo,
                                                 const float* __restrict__ cin,
                                                 float* __restrict__ out) {
  __shared__ char Al[RC * 256];
  __shared__ float2 red[8];
  const int cid = blockIdx.x, b = cid >> 8, c = cid & 255;
  const int t = threadIdx.x;
  const int wave = t >> 6, lane = t & 63;
  const int quad = lane >> 4, l16 = lane & 15;

  float abA[2][16], abB[2][16];
  ln_gates<false>(x, offs, gamma, beta, Wth, bh, Al, red, b, c, cid,
                  abA, abB, nullptr, nullptr);

  // cell emit: cell = a*cin + b, into the ln half of the A-tile (bf16)
  float cell[2][16];
  #pragma unroll
  for (int mi = 0; mi < 2; ++mi) {
    const int mt = wave * 2 + mi;
    #pragma unroll
    for (int nt = 0; nt < 4; ++nt) {
      const int dcol = nt * 16 + l16;
      float ci = cin[(size_t)cid * HD_ + mt * 64 + dcol];
      #pragma unroll
      for (int r = 0; r < 4; ++r) {
        int rowl = mt * 16 + quad * 4 + r;
        float cv = fmaf(abA[mi][nt * 4 + r], ci, abB[mi][nt * 4 + r]);
        cell[mi][nt * 4 + r] = cv;
        *(__bf16*)(Al + swzA(rowl, 128 + dcol * 2)) = (__bf16)cv;
      }
    }
  }
  __syncthreads();

  // og GEMM: A = [x | cell], W = Wto; out = sigm(og)*cell
  #pragma unroll
  for (int mi = 0; mi < 2; ++mi) {
    const int mt = wave * 2 + mi;
    const int arow = mt * 16 + l16;
    f32x4 acc[4];
    #pragma unroll
    for (int nt = 0; nt < 4; ++nt) acc[nt] = (f32x4){0.f, 0.f, 0.f, 0.f};
    #pragma unroll
    for (int ks = 0; ks < 4; ++ks) {
      bf16x8 af = *(const bf16x8*)(Al + swzA(arow, ks * 64 + quad * 16));
      #pragma unroll
      for (int nt = 0; nt < 4; ++nt) {
        bf16x8 bf_ = *(const bf16x8*)(Wto + (nt * 16 + l16) * 128 + ks * 32 + quad * 8);
        acc[nt] = __builtin_amdgcn_mfma_f32_16x16x32_bf16(af, bf_, acc[nt], 0, 0, 0);
      }
    }
    #pragma unroll
    for (int nt = 0; nt < 4; ++nt) {
      const int dcol = nt * 16 + l16;
      float bv = bo[dcol];
      #pragma unroll
      for (int r = 0; r < 4; ++r) {
        int s = quad * 4 + r;
        float og = sigm(acc[nt][r] + bv);
        out[(((size_t)b * S_ + c * LCH + s) * H_ + mt) * D_ + dcol] = og * cell[mi][nt * 4 + r];
      }
    }
  }
}

extern "C" void kernel_launch(void* const* d_in, const int* in_sizes, int n_in,
                              void* d_out, int out_size, void* d_ws, size_t ws_size,
                              hipStream_t stream) {
  const float* x      = (const float*)d_in[0];
  const float* W_hid  = (const float*)d_in[1];
  const float* b_hid  = (const float*)d_in[2];
  const float* W_og   = (const float*)d_in[3];
  const float* b_og   = (const float*)d_in[4];
  const float* gamma  = (const float*)d_in[5];
  const float* beta   = (const float*)d_in[6];
  const float* initcx = (const float*)d_in[7];
  float* out = (float*)d_out;
  float* ws  = (float*)d_ws;

  // ws layout (floats):
  float*  buf0 = ws;                      // sums -> offs (in place)   524288
  float*  cA   = ws + 524288;             //                           524288
  float*  cB   = cA + 524288;             //                           524288
  float*  cin  = cB + 524288;             //                           524288
  float*  gx   = cin + 524288;            // x-offset group sums        32768
  float*  gA   = gx + 32768;              // cell group compose A       32768
  float*  gB   = gA + 32768;              // cell group compose B       32768
  __bf16* Wth  = (__bf16*)(gB + 32768);   // [192][128] bf16
  __bf16* Wto  = Wth + 24576;             // [64][128] bf16

  k_wt         <<<128,  256, 0, stream>>>(W_hid, W_og, Wth, Wto);
  k_chunk_sums <<<1024, 512, 0, stream>>>(x, buf0);
  kx_l1        <<<128,  256, 0, stream>>>(buf0, gx);
  kx_l2        <<<8,    256, 0, stream>>>(gx);
  kx_l3        <<<128,  256, 0, stream>>>(buf0, gx);
  k_gates_f    <<<1024, 256, 0, stream>>>(x, buf0, gamma, beta, Wth, b_hid, cA, cB);
  kc_l1        <<<128,  256, 0, stream>>>(cA, cB, gA, gB);
  kc_l2        <<<8,    256, 0, stream>>>(gA, gB, initcx);
  kc_l3        <<<128,  256, 0, stream>>>(cA, cB, gA, cin);
  k_og_f       <<<1024, 256, 0, stream>>>(x, buf0, gamma, beta, Wth, Wto,
                                          b_hid, b_og, cin, out);
}

// Round 4
// 251.205 us; speedup vs baseline: 1.0174x; 1.0174x over previous
//
#include <hip/hip_runtime.h>
#include <math.h>

#define S_   4096
#define H_   8
#define D_   64
#define HD_  512
#define NCH  256   // chunks per batch
#define LCH  16    // seq steps per chunk
#define RC   128   // rows per chunk = LCH*H_  (h-major: row = h*16 + s)
#define NCOL 2048  // scan columns = B * H * D

typedef __bf16 bf16x8 __attribute__((ext_vector_type(8)));
typedef __bf16 bf16x2 __attribute__((ext_vector_type(2)));
typedef float  f32x4  __attribute__((ext_vector_type(4)));

__device__ __forceinline__ float sigm(float v) { return 1.f / (1.f + __expf(-v)); }

// XOR-swizzled byte offset into the 128x128 bf16 A-tile (row stride 256B).
__device__ __forceinline__ int swzA(int row, int bytecol) {
  return row * 256 + (bytecol ^ ((row & 7) << 4));
}

// ---------------- K0: transpose weights to bf16 [n][k] ----------------
__global__ __launch_bounds__(256) void k_wt(const float* __restrict__ Wh,
                                            const float* __restrict__ Wo,
                                            __bf16* __restrict__ Wth,
                                            __bf16* __restrict__ Wto) {
  int idx = blockIdx.x * 256 + threadIdx.x;   // 0..32767
  if (idx < 24576) {
    int k = idx / 192, n = idx % 192;
    Wth[n * 128 + k] = (__bf16)Wh[idx];
  } else {
    int j = idx - 24576;                       // 0..8191, W_og[k][n], n<64
    int k = j >> 6, n = j & 63;
    Wto[n * 128 + k] = (__bf16)Wo[j];
  }
}

// ---------------- K1: per-chunk sums of x ----------------
__global__ __launch_bounds__(512) void k_chunk_sums(const float* __restrict__ x,
                                                    float* __restrict__ sums) {
  const int b = blockIdx.x >> 8, c = blockIdx.x & 255;
  const int t = threadIdx.x;
  const float* p = x + ((size_t)b * S_ + c * LCH) * HD_ + t;
  float acc = 0.f;
  #pragma unroll
  for (int i = 0; i < LCH; ++i) acc += p[(size_t)i * HD_];
  sums[((size_t)b * NCH + c) * HD_ + t] = acc;
}

// ---------------- 3-level exclusive scan of chunk sums (x offsets) -----------
__global__ __launch_bounds__(256) void kx_l1(const float* __restrict__ sums,
                                             float* __restrict__ gx) {
  int w = blockIdx.x * 256 + threadIdx.x;    // 0..32767
  int grp = w >> 11, col = w & 2047;
  int b = col >> 9, hd = col & 511;
  float s = 0.f;
  #pragma unroll
  for (int i = 0; i < 16; ++i)
    s += sums[((size_t)(b * NCH + grp * 16 + i)) * HD_ + hd];
  gx[grp * NCOL + col] = s;
}
__global__ __launch_bounds__(256) void kx_l2(float* __restrict__ gx) {
  int col = blockIdx.x * 256 + threadIdx.x;  // 0..2047
  float run = 0.f;
  #pragma unroll
  for (int g = 0; g < 16; ++g) {
    float v = gx[g * NCOL + col];
    gx[g * NCOL + col] = run;
    run += v;
  }
}
__global__ __launch_bounds__(256) void kx_l3(float* __restrict__ sums,
                                             const float* __restrict__ gx) {
  int w = blockIdx.x * 256 + threadIdx.x;
  int grp = w >> 11, col = w & 2047;
  int b = col >> 9, hd = col & 511;
  float run = gx[grp * NCOL + col];
  #pragma unroll
  for (int i = 0; i < 16; ++i) {
    size_t idx = ((size_t)(b * NCH + grp * 16 + i)) * HD_ + hd;
    float v = sums[idx];
    sums[idx] = run;
    run += v;
  }
}

// ---------------- shared device body: LN -> LDS A-tile, gates GEMM, scan -----
// WRITE_TOT=true : write only per-chunk totals cA/cB.
// WRITE_TOT=false: fuse cell-emit — needs cin; fills cell[2][16] (f32) and
//                  writes bf16 cell into the ln half of the LDS A-tile.
template <bool WRITE_TOT>
__device__ __forceinline__ void ln_gates(const float* __restrict__ x,
                                         const float* __restrict__ offs,
                                         const float* __restrict__ gamma,
                                         const float* __restrict__ beta,
                                         const __bf16* __restrict__ Wth,
                                         const float* __restrict__ bh,
                                         char* Al, float2* red,
                                         int b, int c, int cid,
                                         const float* __restrict__ cin,
                                         float (&cell)[2][16],
                                         float* __restrict__ cA,
                                         float* __restrict__ cB) {
  const int t = threadIdx.x;
  const int wave = t >> 6, lane = t & 63;
  const int quad = lane >> 4, l16 = lane & 15;

  // ---- P0: running prefix + LayerNorm -> A=[x|ln] tile in LDS ----
  {
    const int hd0 = 2 * t;                 // adjacent columns, same head/row
    const int h = hd0 >> 6, d0 = hd0 & 63; // d0 even
    float2 rr = *(const float2*)(offs + (size_t)(b * NCH + c) * HD_ + hd0);
    float run0 = rr.x, run1 = rr.y;
    float2 gg = *(const float2*)(gamma + hd0);
    float2 be = *(const float2*)(beta + hd0);
    const size_t xbase = ((size_t)b * S_ + c * LCH) * HD_;
    float2 xv = *(const float2*)(x + xbase + hd0);
    for (int s = 0; s < LCH; ++s) {
      float2 xn = make_float2(0.f, 0.f);
      if (s < LCH - 1) xn = *(const float2*)(x + xbase + (size_t)(s + 1) * HD_ + hd0);
      float v = run0 + run1;
      float v2 = fmaf(run0, run0, run1 * run1);
      #pragma unroll
      for (int o = 32; o; o >>= 1) { v += __shfl_xor(v, o); v2 += __shfl_xor(v2, o); }
      if (lane == 0) red[(s & 1) * 4 + wave] = make_float2(v, v2);
      __syncthreads();
      const float2* rb = red + (s & 1) * 4;
      float s1 = rb[0].x + rb[1].x + rb[2].x + rb[3].x;
      float s2 = rb[0].y + rb[1].y + rb[2].y + rb[3].y;
      float m = s1 * (1.f / HD_);
      float var = fmaf(-m, m, s2 * (1.f / HD_));
      float inv = rsqrtf(var + 1e-5f);
      int row = h * 16 + s;
      bf16x2 px = { (__bf16)xv.x, (__bf16)xv.y };
      bf16x2 pl = { (__bf16)((run0 - m) * inv * gg.x + be.x),
                    (__bf16)((run1 - m) * inv * gg.y + be.y) };
      *(bf16x2*)(Al + swzA(row, d0 * 2)) = px;
      *(bf16x2*)(Al + swzA(row, 128 + d0 * 2)) = pl;
      run0 += xv.x; run1 += xv.y;
      xv = xn;
    }
  }
  __syncthreads();

  // ---- P1: gates GEMM (3 register-lean N-passes) + chunk-local scan ----
  #pragma unroll
  for (int mi = 0; mi < 2; ++mi) {
    const int mt = wave * 2 + mi;          // head
    const int arow = mt * 16 + l16;
    float fv[16], iv[16];
    // pass F (N cols 64..127)
    {
      f32x4 acc[4];
      #pragma unroll
      for (int nt = 0; nt < 4; ++nt) acc[nt] = (f32x4){0.f, 0.f, 0.f, 0.f};
      #pragma unroll
      for (int ks = 0; ks < 4; ++ks) {
        bf16x8 af = *(const bf16x8*)(Al + swzA(arow, ks * 64 + quad * 16));
        #pragma unroll
        for (int nt = 0; nt < 4; ++nt) {
          bf16x8 bf_ = *(const bf16x8*)(Wth + ((4 + nt) * 16 + l16) * 128 + ks * 32 + quad * 8);
          acc[nt] = __builtin_amdgcn_mfma_f32_16x16x32_bf16(af, bf_, acc[nt], 0, 0, 0);
        }
      }
      #pragma unroll
      for (int nt = 0; nt < 4; ++nt) {
        float bb_ = bh[64 + nt * 16 + l16];
        #pragma unroll
        for (int r = 0; r < 4; ++r) fv[nt * 4 + r] = sigm(acc[nt][r] + bb_);
      }
    }
    // pass I (N cols 0..63)
    {
      f32x4 acc[4];
      #pragma unroll
      for (int nt = 0; nt < 4; ++nt) acc[nt] = (f32x4){0.f, 0.f, 0.f, 0.f};
      #pragma unroll
      for (int ks = 0; ks < 4; ++ks) {
        bf16x8 af = *(const bf16x8*)(Al + swzA(arow, ks * 64 + quad * 16));
        #pragma unroll
        for (int nt = 0; nt < 4; ++nt) {
          bf16x8 bf_ = *(const bf16x8*)(Wth + (nt * 16 + l16) * 128 + ks * 32 + quad * 8);
          acc[nt] = __builtin_amdgcn_mfma_f32_16x16x32_bf16(af, bf_, acc[nt], 0, 0, 0);
        }
      }
      #pragma unroll
      for (int nt = 0; nt < 4; ++nt) {
        float bb_ = bh[nt * 16 + l16];
        #pragma unroll
        for (int r = 0; r < 4; ++r) iv[nt * 4 + r] = sigm(acc[nt][r] + bb_);
      }
    }
    // pass H (N cols 128..191): iv becomes g = sigm(i)*relu(h)
    {
      f32x4 acc[4];
      #pragma unroll
      for (int nt = 0; nt < 4; ++nt) acc[nt] = (f32x4){0.f, 0.f, 0.f, 0.f};
      #pragma unroll
      for (int ks = 0; ks < 4; ++ks) {
        bf16x8 af = *(const bf16x8*)(Al + swzA(arow, ks * 64 + quad * 16));
        #pragma unroll
        for (int nt = 0; nt < 4; ++nt) {
          bf16x8 bf_ = *(const bf16x8*)(Wth + ((8 + nt) * 16 + l16) * 128 + ks * 32 + quad * 8);
          acc[nt] = __builtin_amdgcn_mfma_f32_16x16x32_bf16(af, bf_, acc[nt], 0, 0, 0);
        }
      }
      #pragma unroll
      for (int nt = 0; nt < 4; ++nt) {
        float bb_ = bh[128 + nt * 16 + l16];
        #pragma unroll
        for (int r = 0; r < 4; ++r)
          iv[nt * 4 + r] = iv[nt * 4 + r] * fmaxf(acc[nt][r] + bb_, 0.f);
      }
    }
    // segmented affine scan over s (4 regs x 4 quads)
    #pragma unroll
    for (int nt = 0; nt < 4; ++nt) {
      float a = 1.f, bb2 = 0.f, pa[4], pb[4];
      #pragma unroll
      for (int r = 0; r < 4; ++r) {
        float fvv = fv[nt * 4 + r], gvv = iv[nt * 4 + r];
        a = fvv * a;
        bb2 = fmaf(fvv, bb2, gvv);
        pa[r] = a; pb[r] = bb2;
      }
      if constexpr (WRITE_TOT) {
        float TA = 1.f, TB = 0.f;
        #pragma unroll
        for (int q = 0; q < 4; ++q) {
          float Aq = __shfl(a, q * 16 + l16, 64);
          float Bq = __shfl(bb2, q * 16 + l16, 64);
          TB = fmaf(Aq, TB, Bq);
          TA = Aq * TA;
        }
        if (quad == 0) {
          cA[(size_t)cid * HD_ + mt * 64 + nt * 16 + l16] = TA;
          cB[(size_t)cid * HD_ + mt * 64 + nt * 16 + l16] = TB;
        }
      } else {
        float exA = 1.f, exB = 0.f;
        #pragma unroll
        for (int q = 0; q < 3; ++q) {
          float Aq = __shfl(a, q * 16 + l16, 64);
          float Bq = __shfl(bb2, q * 16 + l16, 64);
          if (q < quad) { exB = fmaf(Aq, exB, Bq); exA = Aq * exA; }
        }
        // fused cell-emit: cell = pa*(exA*ci + exB) + pb
        const int dcol = nt * 16 + l16;
        float ci = cin[(size_t)cid * HD_ + mt * 64 + dcol];
        float u = fmaf(exA, ci, exB);
        #pragma unroll
        for (int r = 0; r < 4; ++r) {
          float cv = fmaf(pa[r], u, pb[r]);
          cell[mi][nt * 4 + r] = cv;
          int rowl = mt * 16 + quad * 4 + r;
          *(__bf16*)(Al + swzA(rowl, 128 + dcol * 2)) = (__bf16)cv;
        }
      }
    }
  }
}

// ---------------- K4: LN + gates GEMM + chunk scan -> cA/cB only -------------
__global__ __launch_bounds__(256) void k_gates_f(const float* __restrict__ x,
                                                 const float* __restrict__ offs,
                                                 const float* __restrict__ gamma,
                                                 const float* __restrict__ beta,
                                                 const __bf16* __restrict__ Wth,
                                                 const float* __restrict__ bh,
                                                 float* __restrict__ cA,
                                                 float* __restrict__ cB) {
  __shared__ char Al[RC * 256];
  __shared__ float2 red[8];
  const int cid = blockIdx.x, b = cid >> 8, c = cid & 255;
  float cell[2][16];   // unused in this instantiation
  ln_gates<true>(x, offs, gamma, beta, Wth, bh, Al, red, b, c, cid,
                 nullptr, cell, cA, cB);
}

// ---------------- 3-level cross-chunk cell scan ------------------------------
__global__ __launch_bounds__(256) void kc_l1(const float* __restrict__ cA,
                                             const float* __restrict__ cB,
                                             float* __restrict__ gA,
                                             float* __restrict__ gB) {
  int w = blockIdx.x * 256 + threadIdx.x;
  int grp = w >> 11, col = w & 2047;
  int b = col >> 9, hd = col & 511;
  float Ag = 1.f, Bg = 0.f;
  #pragma unroll
  for (int i = 0; i < 16; ++i) {
    size_t idx = ((size_t)(b * NCH + grp * 16 + i)) * HD_ + hd;
    float Ac = cA[idx], Bc = cB[idx];
    Bg = fmaf(Ac, Bg, Bc);
    Ag = Ac * Ag;
  }
  gA[grp * NCOL + col] = Ag;
  gB[grp * NCOL + col] = Bg;
}
__global__ __launch_bounds__(256) void kc_l2(float* __restrict__ gA,
                                             const float* __restrict__ gB,
                                             const float* __restrict__ initcx) {
  int col = blockIdx.x * 256 + threadIdx.x;   // 0..2047
  int hd = col & 511;
  float run = initcx[hd];
  #pragma unroll
  for (int g = 0; g < 16; ++g) {
    float Ag = gA[g * NCOL + col], Bg = gB[g * NCOL + col];
    gA[g * NCOL + col] = run;                 // group run-in value
    run = fmaf(Ag, run, Bg);
  }
}
__global__ __launch_bounds__(256) void kc_l3(const float* __restrict__ cA,
                                             const float* __restrict__ cB,
                                             const float* __restrict__ gA,
                                             float* __restrict__ cin) {
  int w = blockIdx.x * 256 + threadIdx.x;
  int grp = w >> 11, col = w & 2047;
  int b = col >> 9, hd = col & 511;
  float run = gA[grp * NCOL + col];
  #pragma unroll
  for (int i = 0; i < 16; ++i) {
    size_t idx = ((size_t)(b * NCH + grp * 16 + i)) * HD_ + hd;
    cin[idx] = run;
    run = fmaf(cA[idx], run, cB[idx]);
  }
}

// ---------------- K6: recompute LN+gates, fused cell emit, og GEMM, out ------
__global__ __launch_bounds__(256) void k_og_f(const float* __restrict__ x,
                                              const float* __restrict__ offs,
                                              const float* __restrict__ gamma,
                                              const float* __restrict__ beta,
                                              const __bf16* __restrict__ Wth,
                                              const __bf16* __restrict__ Wto,
                                              const float* __restrict__ bh,
                                              const float* __restrict__ bo,
                                              const float* __restrict__ cin,
                                              float* __restrict__ out) {
  __shared__ char Al[RC * 256];
  __shared__ float2 red[8];
  const int cid = blockIdx.x, b = cid >> 8, c = cid & 255;
  const int t = threadIdx.x;
  const int wave = t >> 6, lane = t & 63;
  const int quad = lane >> 4, l16 = lane & 15;

  float cell[2][16];
  ln_gates<false>(x, offs, gamma, beta, Wth, bh, Al, red, b, c, cid,
                  cin, cell, nullptr, nullptr);
  // No barrier needed: each wave reads only its own head's 32 A-tile rows,
  // which only it writes (LN phase and cell-emit are wave-local by row).

  // og GEMM: A = [x | cell], W = Wto; out = sigm(og)*cell
  #pragma unroll
  for (int mi = 0; mi < 2; ++mi) {
    const int mt = wave * 2 + mi;
    const int arow = mt * 16 + l16;
    f32x4 acc[4];
    #pragma unroll
    for (int nt = 0; nt < 4; ++nt) acc[nt] = (f32x4){0.f, 0.f, 0.f, 0.f};
    #pragma unroll
    for (int ks = 0; ks < 4; ++ks) {
      bf16x8 af = *(const bf16x8*)(Al + swzA(arow, ks * 64 + quad * 16));
      #pragma unroll
      for (int nt = 0; nt < 4; ++nt) {
        bf16x8 bf_ = *(const bf16x8*)(Wto + (nt * 16 + l16) * 128 + ks * 32 + quad * 8);
        acc[nt] = __builtin_amdgcn_mfma_f32_16x16x32_bf16(af, bf_, acc[nt], 0, 0, 0);
      }
    }
    #pragma unroll
    for (int nt = 0; nt < 4; ++nt) {
      const int dcol = nt * 16 + l16;
      float bv = bo[dcol];
      #pragma unroll
      for (int r = 0; r < 4; ++r) {
        int s = quad * 4 + r;
        float og = sigm(acc[nt][r] + bv);
        out[(((size_t)b * S_ + c * LCH + s) * H_ + mt) * D_ + dcol] = og * cell[mi][nt * 4 + r];
      }
    }
  }
}

extern "C" void kernel_launch(void* const* d_in, const int* in_sizes, int n_in,
                              void* d_out, int out_size, void* d_ws, size_t ws_size,
                              hipStream_t stream) {
  const float* x      = (const float*)d_in[0];
  const float* W_hid  = (const float*)d_in[1];
  const float* b_hid  = (const float*)d_in[2];
  const float* W_og   = (const float*)d_in[3];
  const float* b_og   = (const float*)d_in[4];
  const float* gamma  = (const float*)d_in[5];
  const float* beta   = (const float*)d_in[6];
  const float* initcx = (const float*)d_in[7];
  float* out = (float*)d_out;
  float* ws  = (float*)d_ws;

  // ws layout (floats):
  float*  buf0 = ws;                      // sums -> offs (in place)   524288
  float*  cA   = ws + 524288;             //                           524288
  float*  cB   = cA + 524288;             //                           524288
  float*  cin  = cB + 524288;             //                           524288
  float*  gx   = cin + 524288;            // x-offset group sums        32768
  float*  gA   = gx + 32768;              // cell group compose A       32768
  float*  gB   = gA + 32768;              // cell group compose B       32768
  __bf16* Wth  = (__bf16*)(gB + 32768);   // [192][128] bf16
  __bf16* Wto  = Wth + 24576;             // [64][128] bf16

  k_wt         <<<128,  256, 0, stream>>>(W_hid, W_og, Wth, Wto);
  k_chunk_sums <<<1024, 512, 0, stream>>>(x, buf0);
  kx_l1        <<<128,  256, 0, stream>>>(buf0, gx);
  kx_l2        <<<8,    256, 0, stream>>>(gx);
  kx_l3        <<<128,  256, 0, stream>>>(buf0, gx);
  k_gates_f    <<<1024, 256, 0, stream>>>(x, buf0, gamma, beta, Wth, b_hid, cA, cB);
  kc_l1        <<<128,  256, 0, stream>>>(cA, cB, gA, gB);
  kc_l2        <<<8,    256, 0, stream>>>(gA, gB, initcx);
  kc_l3        <<<128,  256, 0, stream>>>(cA, cB, gA, cin);
  k_og_f       <<<1024, 256, 0, stream>>>(x, buf0, gamma, beta, Wth, Wto,
                                          b_hid, b_og, cin, out);
}